// Round 16
// baseline (1116.047 us; speedup 1.0000x reference)
//
#include <hip/hip_runtime.h>

typedef __bf16 bf16;
typedef __bf16 bf16x8 __attribute__((ext_vector_type(8)));
typedef float f32x4 __attribute__((ext_vector_type(4)));
typedef unsigned uint32x4 __attribute__((ext_vector_type(4)));

#define Tt 64
#define Bb 1024
#define Dd 128
#define Ee 256
#define Hh 512
#define H3 1536

__device__ __forceinline__ float sigmf(float x) { return 1.0f / (1.0f + __expf(-x)); }
__device__ __forceinline__ float tanhfast(float x) {
    float e = __expf(2.0f * x);
    return 1.0f - 2.0f / (e + 1.0f);
}

// agent-scope (device-coherent) ops; sc1 = bypass L2 to the memory-side L3.
#define LD_SC(dst, bp, OFF) \
    asm volatile("global_load_dwordx4 %0, %1, off offset:" #OFF " sc1" : "=&v"(dst) : "v"(bp))
#define ST_SC(bp, OFF, val) \
    asm volatile("global_store_short %0, %1, off offset:" #OFF " sc1" :: "v"(bp), "v"(val))

// sentinel test: any bf16 element == 0xFFFF (buffers are 0xFF-initialized; gate outputs
// are always finite so real data can never equal the sentinel)
__device__ __forceinline__ bool has_sent(bf16x8 v) {
    uint32x4 w = __builtin_bit_cast(uint32x4, v);
    bool m = false;
#pragma unroll
    for (int i = 0; i < 4; ++i) {
        m = m || ((w[i] & 0xFFFFu) == 0xFFFFu) || ((w[i] >> 16) == 0xFFFFu);
    }
    return m;
}

// ---------------- fused weight prep: f32 [K][N] -> bf16 [N][K] for all 6 weights ----------------
__global__ void k_prep(const float* __restrict__ We, const float* __restrict__ Wie, const float* __restrict__ Whe,
                       const float* __restrict__ Wid, const float* __restrict__ Whd, const float* __restrict__ Wo,
                       bf16* __restrict__ dWe, bf16* __restrict__ dWie, bf16* __restrict__ dWhe,
                       bf16* __restrict__ dWid, bf16* __restrict__ dWhd, bf16* __restrict__ dWo) {
    long i = (long)blockIdx.x * 256 + threadIdx.x;
    const float* s;
    bf16* d;
    int K, N;
    if (i < 32768) { s = We; d = dWe; K = Dd; N = Ee; }
    else if ((i -= 32768) < 393216) { s = Wie; d = dWie; K = Ee; N = H3; }
    else if ((i -= 393216) < 786432) { s = Whe; d = dWhe; K = Hh; N = H3; }
    else if ((i -= 786432) < 393216) { s = Wid; d = dWid; K = Ee; N = H3; }
    else if ((i -= 393216) < 786432) { s = Whd; d = dWhd; K = Hh; N = H3; }
    else if ((i -= 786432) < 65536) { s = Wo; d = dWo; K = Hh; N = Dd; }
    else return;
    int n = (int)(i / K), k = (int)(i - (long)n * K);
    d[i] = (bf16)s[(size_t)k * N + n];
}

// ---------------- embed: relu(x @ W_emb + b); past (z=0) and future (z=1) fused ----------------
__global__ __launch_bounds__(256) void k_embed(const float* __restrict__ xP, const float* __restrict__ xF,
                                               const bf16* __restrict__ WT, const float* __restrict__ bias,
                                               bf16* __restrict__ oP, bf16* __restrict__ oF) {
    const int lane = threadIdx.x & 63, wv = threadIdx.x >> 6;
    const float* x = blockIdx.z ? xF : xP;
    bf16* o = blockIdx.z ? oF : oP;
    const int m0w = blockIdx.x * 128 + wv * 32;
    const int c0 = blockIdx.y * 64;
    const int koff = (lane >> 4) * 8;
    f32x4 acc[2][4];
#pragma unroll
    for (int m = 0; m < 2; ++m)
#pragma unroll
        for (int s = 0; s < 4; ++s) acc[m][s] = f32x4{0.f, 0.f, 0.f, 0.f};

    const float* xp0 = x + (size_t)(m0w + (lane & 15)) * Dd + koff;
#pragma unroll
    for (int kc = 0; kc < 4; ++kc) {
        bf16x8 a0, a1;
        {
            float4 f0 = *(const float4*)(xp0 + kc * 32);
            float4 f1 = *(const float4*)(xp0 + kc * 32 + 4);
            a0[0] = (bf16)f0.x; a0[1] = (bf16)f0.y; a0[2] = (bf16)f0.z; a0[3] = (bf16)f0.w;
            a0[4] = (bf16)f1.x; a0[5] = (bf16)f1.y; a0[6] = (bf16)f1.z; a0[7] = (bf16)f1.w;
            float4 g0 = *(const float4*)(xp0 + 16 * Dd + kc * 32);
            float4 g1 = *(const float4*)(xp0 + 16 * Dd + kc * 32 + 4);
            a1[0] = (bf16)g0.x; a1[1] = (bf16)g0.y; a1[2] = (bf16)g0.z; a1[3] = (bf16)g0.w;
            a1[4] = (bf16)g1.x; a1[5] = (bf16)g1.y; a1[6] = (bf16)g1.z; a1[7] = (bf16)g1.w;
        }
#pragma unroll
        for (int s = 0; s < 4; ++s) {
            bf16x8 b = *(const bf16x8*)(WT + (size_t)(c0 + s * 16 + (lane & 15)) * Dd + kc * 32 + koff);
            acc[0][s] = __builtin_amdgcn_mfma_f32_16x16x32_bf16(a0, b, acc[0][s], 0, 0, 0);
            acc[1][s] = __builtin_amdgcn_mfma_f32_16x16x32_bf16(a1, b, acc[1][s], 0, 0, 0);
        }
    }
#pragma unroll
    for (int m = 0; m < 2; ++m)
#pragma unroll
        for (int s = 0; s < 4; ++s) {
            int col = c0 + s * 16 + (lane & 15);
            float bv = bias[col];
#pragma unroll
            for (int r = 0; r < 4; ++r) {
                int row = m0w + m * 16 + (lane >> 4) * 4 + r;
                o[(size_t)row * Ee + col] = (bf16)fmaxf(acc[m][s][r] + bv, 0.0f);
            }
        }
}

// ---------------- persistent cooperative GRU v10: ack-free flags + sentinel-verified data ----------------
// Round-11 skeleton (best, 923us): 256 blocks = 16 groups (im) x 16 col-blocks (in), XCD remap,
// 4 waves/block (rh), MFMA 16x16x32, weights in LDS, per-peer pipelined HSTEP waits, 64B-stride flags.
// CHANGES: (1) per-step buffers henc[64]/hmid/ys[64] (0xFF sentinel-init) -> no anti-deps, no mid wait;
// (2) signal drops vmcnt(0) -> flag flies concurrently with data stores (store-ack off the chain);
// (3) consumers sentinel-verify loaded chunks, re-loading stragglers (rare; flag trip ~= data trip).
// Deadlock-impossible: producers never block; consumers wait only on step t-1 data.
__global__ __launch_bounds__(256, 1) void k_gru_all(
    const bf16* __restrict__ embP, const bf16* __restrict__ embF, const float* __restrict__ noise,
    const bf16* __restrict__ WihE, const bf16* __restrict__ WhhE,
    const float* __restrict__ bIhE, const float* __restrict__ bHhE,
    const bf16* __restrict__ WihD, const bf16* __restrict__ WhhD,
    const float* __restrict__ bIhD, const float* __restrict__ bHhD,
    bf16* __restrict__ henc, bf16* __restrict__ hmid, bf16* __restrict__ ys, unsigned* __restrict__ flags) {
    __shared__ bf16 Wih[6 * 8 * 64 * 8];    // 49152 B: [s=gate*2+f][kc8][lane]x8
    __shared__ bf16 Whh[6 * 16 * 64 * 8];   // 98304 B: [s=gate*2+f][kc16][lane]x8
    const int tid = threadIdx.x;
    const int lane = tid & 63, rh = tid >> 6;    // rh 0..3
    const int bid = blockIdx.x;
    const int im = (bid & 7) * 2 + (bid >> 7);   // group 0..15; xcd = bid&7
    const int in = (bid >> 3) & 15;              // col block 0..15
    const int rowb = im * 64 + rh * 16;
    const int arow0 = rowb + (lane & 15);
    const int koff = (lane >> 4) * 8;
    const int colc0 = in * 32 + (lane & 15);     // f=0 column; f=1 adds 16
    unsigned* dom = flags + ((size_t)im * 4 + rh) * 16 * 16;  // 16 flags x 64B (round-11 layout)

    const bf16x8* WihV = (const bf16x8*)Wih;
    const bf16x8* WhhV = (const bf16x8*)Whh;

    auto stage = [&](const bf16* WT, int Kdim, int KC, bf16* lds) {
        int total = 6 * KC * 64;
        for (int idx = tid; idx < total; idx += 256) {
            int ln = idx & 63;
            int kc = (idx >> 6) % KC;
            int s = (idx >> 6) / KC;
            int gate = s >> 1, f = s & 1;
            int col = gate * Hh + in * 32 + f * 16 + (ln & 15);
            int k = kc * 32 + (ln >> 4) * 8;
            *(bf16x8*)(lds + (size_t)idx * 8) = *(const bf16x8*)(WT + (size_t)col * Kdim + k);
        }
    };

    float bi[3][2], bh[3][2];
    auto load_bias = [&](const float* bIh, const float* bHh) {
#pragma unroll
        for (int g = 0; g < 3; ++g)
#pragma unroll
            for (int f = 0; f < 2; ++f) {
                int c = g * Hh + colc0 + f * 16;
                bi[g][f] = bIh[c];
                bh[g][f] = bHh[c];
            }
    };

    // ack-FREE release: flag issues right after data stores (no vmcnt drain on the chain).
    // Same-address flag stores from one wave are ordered -> seq stays monotonic.
    auto signal = [&](unsigned seq) {
        if (lane == 0) {
            unsigned* fp = dom + in * 16;
            asm volatile("global_store_dword %0, %1, off sc1" :: "v"(fp), "v"(seq) : "memory");
        }
    };
    // one poll: lane k loads peer (k&15)'s flag -> 64-bit ballot
    auto poll = [&](unsigned seq) -> unsigned long long {
        unsigned v;
        const unsigned* fp = dom + (lane & 15) * 16;
        asm volatile("global_load_dword %0, %1, off sc1\n\ts_waitcnt vmcnt(0)"
                     : "=&v"(v) : "v"(fp) : "memory");
        return __ballot((int)(v >= seq));
    };

    f32x4 aR[2], aZ[2], aNX[2], aNH[2];
    auto zacc = [&]() {
#pragma unroll
        for (int f = 0; f < 2; ++f) {
            aR[f] = f32x4{0.f, 0.f, 0.f, 0.f};
            aZ[f] = f32x4{0.f, 0.f, 0.f, 0.f};
            aNX[f] = f32x4{0.f, 0.f, 0.f, 0.f};
            aNH[f] = f32x4{0.f, 0.f, 0.f, 0.f};
        }
    };

    auto xp_phase = [&](const bf16* xp) {
        const bf16* ap = xp + (size_t)arow0 * Ee + koff;
#pragma unroll
        for (int kc = 0; kc < 8; ++kc) {
            bf16x8 a = *(const bf16x8*)(ap + kc * 32);
#pragma unroll
            for (int f = 0; f < 2; ++f) {
                aR[f] = __builtin_amdgcn_mfma_f32_16x16x32_bf16(a, WihV[((0 + f) * 8 + kc) * 64 + lane], aR[f], 0, 0, 0);
                aZ[f] = __builtin_amdgcn_mfma_f32_16x16x32_bf16(a, WihV[((2 + f) * 8 + kc) * 64 + lane], aZ[f], 0, 0, 0);
                aNX[f] = __builtin_amdgcn_mfma_f32_16x16x32_bf16(a, WihV[((4 + f) * 8 + kc) * 64 + lane], aNX[f], 0, 0, 0);
            }
        }
    };

    // hW: per-peer pipelined flag waits (chunk kc=p <- peer block p), then sentinel verify
    // (re-load stragglers whose data hasn't landed yet despite the flag).
    auto hw_phase = [&](const bf16* hp, unsigned seq) {
        const bf16* h0p = hp + (size_t)arow0 * Hh + koff;
        bf16x8 h0[16];
        unsigned long long rdy = poll(seq);
#define HSTEP(p, OFF) \
        while (!((rdy >> p) & 1ULL)) { __builtin_amdgcn_s_sleep(1); rdy = poll(seq); } \
        LD_SC(h0[p], h0p, OFF);
        HSTEP(0, 0)    HSTEP(1, 64)   HSTEP(2, 128)  HSTEP(3, 192)
        HSTEP(4, 256)  HSTEP(5, 320)  HSTEP(6, 384)  HSTEP(7, 448)
        HSTEP(8, 512)  HSTEP(9, 576)  HSTEP(10, 640) HSTEP(11, 704)
        HSTEP(12, 768) HSTEP(13, 832) HSTEP(14, 896) HSTEP(15, 960)
#undef HSTEP
        asm volatile("s_waitcnt vmcnt(0)" ::: "memory");
        // sentinel verification: retry any chunk whose stores hadn't landed yet
        unsigned fail = 0;
#define CK0(p) fail |= ((unsigned)__any((int)has_sent(h0[p]))) << p;
        CK0(0) CK0(1) CK0(2) CK0(3) CK0(4) CK0(5) CK0(6) CK0(7)
        CK0(8) CK0(9) CK0(10) CK0(11) CK0(12) CK0(13) CK0(14) CK0(15)
#undef CK0
#pragma unroll 1
        while (fail) {
            __builtin_amdgcn_s_sleep(1);
#define RT(p, OFF) if (fail & (1u << p)) { LD_SC(h0[p], h0p, OFF); }
            RT(0, 0)    RT(1, 64)   RT(2, 128)  RT(3, 192)
            RT(4, 256)  RT(5, 320)  RT(6, 384)  RT(7, 448)
            RT(8, 512)  RT(9, 576)  RT(10, 640) RT(11, 704)
            RT(12, 768) RT(13, 832) RT(14, 896) RT(15, 960)
#undef RT
            asm volatile("s_waitcnt vmcnt(0)" ::: "memory");
            unsigned nf = 0;
#define CK(p) if (fail & (1u << p)) { nf |= ((unsigned)__any((int)has_sent(h0[p]))) << p; }
            CK(0) CK(1) CK(2) CK(3) CK(4) CK(5) CK(6) CK(7)
            CK(8) CK(9) CK(10) CK(11) CK(12) CK(13) CK(14) CK(15)
#undef CK
            fail = nf;
        }
        __builtin_amdgcn_sched_barrier(0);
#pragma unroll
        for (int kc = 0; kc < 16; ++kc) {
#pragma unroll
            for (int f = 0; f < 2; ++f) {
                aR[f] = __builtin_amdgcn_mfma_f32_16x16x32_bf16(h0[kc], WhhV[((0 + f) * 16 + kc) * 64 + lane], aR[f], 0, 0, 0);
                aZ[f] = __builtin_amdgcn_mfma_f32_16x16x32_bf16(h0[kc], WhhV[((2 + f) * 16 + kc) * 64 + lane], aZ[f], 0, 0, 0);
                aNH[f] = __builtin_amdgcn_mfma_f32_16x16x32_bf16(h0[kc], WhhV[((4 + f) * 16 + kc) * 64 + lane], aNH[f], 0, 0, 0);
            }
        }
    };

    float hreg[8];
#pragma unroll
    for (int i = 0; i < 8; ++i) hreg[i] = 0.0f;

    auto epi = [&](bf16* op) {
#pragma unroll
        for (int f = 0; f < 2; ++f) {
            bf16* stb = op + (size_t)(rowb + (lane >> 4) * 4) * Hh + colc0 + f * 16;
            unsigned short us[4];
#pragma unroll
            for (int r = 0; r < 4; ++r) {
                float rg = sigmf(aR[f][r] + bi[0][f] + bh[0][f]);
                float zg = sigmf(aZ[f][r] + bi[1][f] + bh[1][f]);
                float ng = tanhfast(aNX[f][r] + bi[2][f] + rg * (aNH[f][r] + bh[2][f]));
                float hv = (1.0f - zg) * ng + zg * hreg[f * 4 + r];
                hreg[f * 4 + r] = hv;
                us[r] = __builtin_bit_cast(unsigned short, (bf16)hv);
            }
            ST_SC(stb, 0, us[0]);
            ST_SC(stb, 1024, us[1]);
            ST_SC(stb, 2048, us[2]);
            ST_SC(stb, 3072, us[3]);
        }
    };

    // ---------- encoder: step t reads henc[t-1], writes henc[t] ----------
    stage(WihE, Ee, 8, Wih);
    stage(WhhE, Hh, 16, Whh);
    load_bias(bIhE, bHhE);
    __syncthreads();

#pragma unroll 1
    for (int t = 0; t < Tt; ++t) {
        zacc();
        xp_phase(embP + (size_t)t * Bb * Ee);
        if (t > 0) hw_phase(henc + (size_t)(t - 1) * Bb * Hh, (unsigned)t);
        epi(henc + (size_t)t * Bb * Hh);
        signal((unsigned)(t + 1));  // seq 1..64, ack-free
    }

    // ---------- hidden = h_enc + noise -> hmid (fresh buffer, no wait needed) ----------
    {
#pragma unroll
        for (int f = 0; f < 2; ++f) {
            bf16* stb = hmid + (size_t)(rowb + (lane >> 4) * 4) * Hh + colc0 + f * 16;
            unsigned short us[4];
#pragma unroll
            for (int r = 0; r < 4; ++r) {
                int row = rowb + (lane >> 4) * 4 + r;
                float v = hreg[f * 4 + r] + noise[(size_t)row * Hh + colc0 + f * 16];
                hreg[f * 4 + r] = v;
                us[r] = __builtin_bit_cast(unsigned short, (bf16)v);
            }
            ST_SC(stb, 0, us[0]);
            ST_SC(stb, 1024, us[1]);
            ST_SC(stb, 2048, us[2]);
            ST_SC(stb, 3072, us[3]);
        }
    }
    __syncthreads();  // all waves of this block past their enc LDS reads
    stage(WihD, Ee, 8, Wih);
    stage(WhhD, Hh, 16, Whh);
    __syncthreads();  // decoder LDS staged before any wave's dec reads
    load_bias(bIhD, bHhD);
    signal((unsigned)(Tt + 1));  // seq 65: hmid stores issued long ago (staging covered flight)

    // ---------- decoder: step t reads ys[t-1] (or hmid), writes ys[t] ----------
#pragma unroll 1
    for (int t = 0; t < Tt; ++t) {
        zacc();
        if (t > 0) xp_phase(embF + (size_t)(t - 1) * Bb * Ee);
        hw_phase(t ? ys + (size_t)(t - 1) * Bb * Hh : hmid, (unsigned)(Tt + 1 + t));  // seq 65+t
        epi(ys + (size_t)t * Bb * Hh);
        if (t < Tt - 1) signal((unsigned)(Tt + 2 + t));  // seq 66..128
    }
}

// ---------------- out = ys @ W_out + b_out; 64 rows/wave ----------------
__global__ __launch_bounds__(256) void k_out(const bf16* __restrict__ ys, const bf16* __restrict__ WT,
                                             const float* __restrict__ bias, float* __restrict__ out) {
    const int lane = threadIdx.x & 63, wv = threadIdx.x >> 6;
    const int m0w = blockIdx.x * 256 + wv * 64;
    const int c0 = blockIdx.y * 64;
    const int koff = (lane >> 4) * 8;
    f32x4 acc[4][4];
#pragma unroll
    for (int m = 0; m < 4; ++m)
#pragma unroll
        for (int s = 0; s < 4; ++s) acc[m][s] = f32x4{0.f, 0.f, 0.f, 0.f};

    const bf16* ap = ys + (size_t)(m0w + (lane & 15)) * Hh + koff;
#pragma unroll
    for (int kc = 0; kc < 16; ++kc) {
        bf16x8 a0 = *(const bf16x8*)(ap + kc * 32);
        bf16x8 a1 = *(const bf16x8*)(ap + 16 * Hh + kc * 32);
        bf16x8 a2 = *(const bf16x8*)(ap + 32 * Hh + kc * 32);
        bf16x8 a3 = *(const bf16x8*)(ap + 48 * Hh + kc * 32);
#pragma unroll
        for (int s = 0; s < 4; ++s) {
            bf16x8 b = *(const bf16x8*)(WT + (size_t)(c0 + s * 16 + (lane & 15)) * Hh + kc * 32 + koff);
            acc[0][s] = __builtin_amdgcn_mfma_f32_16x16x32_bf16(a0, b, acc[0][s], 0, 0, 0);
            acc[1][s] = __builtin_amdgcn_mfma_f32_16x16x32_bf16(a1, b, acc[1][s], 0, 0, 0);
            acc[2][s] = __builtin_amdgcn_mfma_f32_16x16x32_bf16(a2, b, acc[2][s], 0, 0, 0);
            acc[3][s] = __builtin_amdgcn_mfma_f32_16x16x32_bf16(a3, b, acc[3][s], 0, 0, 0);
        }
    }
#pragma unroll
    for (int m = 0; m < 4; ++m)
#pragma unroll
        for (int s = 0; s < 4; ++s) {
            int col = c0 + s * 16 + (lane & 15);
            float bv = bias[col];
#pragma unroll
            for (int r = 0; r < 4; ++r) {
                int row = m0w + m * 16 + (lane >> 4) * 4 + r;
                out[(size_t)row * Dd + col] = acc[m][s][r] + bv;
            }
        }
}

extern "C" void kernel_launch(void* const* d_in, const int* in_sizes, int n_in,
                              void* d_out, int out_size, void* d_ws, size_t ws_size,
                              hipStream_t stream) {
    const float* past = (const float*)d_in[0];
    const float* fut = (const float*)d_in[1];
    const float* noise = (const float*)d_in[2];
    const float* W_emb = (const float*)d_in[3];
    const float* b_emb = (const float*)d_in[4];
    const float* W_ih_enc = (const float*)d_in[5];
    const float* W_hh_enc = (const float*)d_in[6];
    const float* b_ih_enc = (const float*)d_in[7];
    const float* b_hh_enc = (const float*)d_in[8];
    const float* W_ih_dec = (const float*)d_in[9];
    const float* W_hh_dec = (const float*)d_in[10];
    const float* b_ih_dec = (const float*)d_in[11];
    const float* b_hh_dec = (const float*)d_in[12];
    const float* W_out = (const float*)d_in[13];
    const float* b_out = (const float*)d_in[14];
    float* out = (float*)d_out;

    char* w = (char*)d_ws;
    auto alloc = [&](size_t bytes) {
        char* p = w;
        w += (bytes + 255) & ~(size_t)255;
        return p;
    };
    bf16* embP = (bf16*)alloc((size_t)Tt * Bb * Ee * 2);
    bf16* embF = (bf16*)alloc((size_t)Tt * Bb * Ee * 2);
    bf16* ys = (bf16*)alloc((size_t)Tt * Bb * Hh * 2);    // per-step decoder h (also k_out input)
    bf16* henc = (bf16*)alloc((size_t)Tt * Bb * Hh * 2);  // per-step encoder h
    bf16* hmid = (bf16*)alloc((size_t)Bb * Hh * 2);
    bf16* WembT = (bf16*)alloc((size_t)Ee * Dd * 2);
    bf16* WihEncT = (bf16*)alloc((size_t)H3 * Ee * 2);
    bf16* WhhEncT = (bf16*)alloc((size_t)H3 * Hh * 2);
    bf16* WihDecT = (bf16*)alloc((size_t)H3 * Ee * 2);
    bf16* WhhDecT = (bf16*)alloc((size_t)H3 * Hh * 2);
    bf16* WoutT = (bf16*)alloc((size_t)Dd * Hh * 2);
    unsigned* flags = (unsigned*)alloc(16 * 4 * 16 * 16 * sizeof(unsigned));  // [im][rh][in], 64B stride

    // weight prep (all six transposes fused)
    k_prep<<<9600, 256, 0, stream>>>(W_emb, W_ih_enc, W_hh_enc, W_ih_dec, W_hh_dec, W_out,
                                     WembT, WihEncT, WhhEncT, WihDecT, WhhDecT, WoutT);

    // embeddings (past + future fused)
    k_embed<<<dim3(Tt * Bb / 128, Ee / 64, 2), 256, 0, stream>>>(past, fut, WembT, b_emb, embP, embF);

    // sentinel-init per-step h buffers + reset flags (re-done on every graph replay)
    hipMemsetAsync(ys, 0xFF, (size_t)Tt * Bb * Hh * 2, stream);
    hipMemsetAsync(henc, 0xFF, (size_t)Tt * Bb * Hh * 2, stream);
    hipMemsetAsync(hmid, 0xFF, (size_t)Bb * Hh * 2, stream);
    hipMemsetAsync(flags, 0, 16 * 4 * 16 * 16 * sizeof(unsigned), stream);

    // cooperative persistent recurrent kernel: 256 blocks x 256 threads
    void* args[] = {(void*)&embP, (void*)&embF, (void*)&noise,
                    (void*)&WihEncT, (void*)&WhhEncT, (void*)&b_ih_enc, (void*)&b_hh_enc,
                    (void*)&WihDecT, (void*)&WhhDecT, (void*)&b_ih_dec, (void*)&b_hh_dec,
                    (void*)&henc, (void*)&hmid, (void*)&ys, (void*)&flags};
    hipLaunchCooperativeKernel((const void*)k_gru_all, dim3(256), dim3(256), args, 0, stream);

    // output projection
    k_out<<<dim3(Tt * Bb / 256, Dd / 64), 256, 0, stream>>>(ys, WoutT, b_out, out);
}

// Round 17
// 1001.401 us; speedup vs baseline: 1.1145x; 1.1145x over previous
//
#include <hip/hip_runtime.h>

typedef __bf16 bf16;
typedef __bf16 bf16x8 __attribute__((ext_vector_type(8)));
typedef float f32x4 __attribute__((ext_vector_type(4)));

#define Tt 64
#define Bb 1024
#define Dd 128
#define Ee 256
#define Hh 512
#define H3 1536

__device__ __forceinline__ float sigmf(float x) { return 1.0f / (1.0f + __expf(-x)); }
__device__ __forceinline__ float tanhfast(float x) {
    float e = __expf(2.0f * x);
    return 1.0f - 2.0f / (e + 1.0f);
}

// agent-scope (device-coherent) ops; sc1 = bypass L2 to the memory-side L3.
#define LD_SC(dst, bp, OFF) \
    asm volatile("global_load_dwordx4 %0, %1, off offset:" #OFF " sc1" : "=&v"(dst) : "v"(bp))
#define ST_SC(bp, OFF, val) \
    asm volatile("global_store_short %0, %1, off offset:" #OFF " sc1" :: "v"(bp), "v"(val))

// ---------------- fused weight prep: f32 [K][N] -> bf16 [N][K] for all 6 weights ----------------
__global__ void k_prep(const float* __restrict__ We, const float* __restrict__ Wie, const float* __restrict__ Whe,
                       const float* __restrict__ Wid, const float* __restrict__ Whd, const float* __restrict__ Wo,
                       bf16* __restrict__ dWe, bf16* __restrict__ dWie, bf16* __restrict__ dWhe,
                       bf16* __restrict__ dWid, bf16* __restrict__ dWhd, bf16* __restrict__ dWo) {
    long i = (long)blockIdx.x * 256 + threadIdx.x;
    const float* s;
    bf16* d;
    int K, N;
    if (i < 32768) { s = We; d = dWe; K = Dd; N = Ee; }
    else if ((i -= 32768) < 393216) { s = Wie; d = dWie; K = Ee; N = H3; }
    else if ((i -= 393216) < 786432) { s = Whe; d = dWhe; K = Hh; N = H3; }
    else if ((i -= 786432) < 393216) { s = Wid; d = dWid; K = Ee; N = H3; }
    else if ((i -= 393216) < 786432) { s = Whd; d = dWhd; K = Hh; N = H3; }
    else if ((i -= 786432) < 65536) { s = Wo; d = dWo; K = Hh; N = Dd; }
    else return;
    int n = (int)(i / K), k = (int)(i - (long)n * K);
    d[i] = (bf16)s[(size_t)k * N + n];
}

// ---------------- embed: relu(x @ W_emb + b); past (z=0) and future (z=1) fused ----------------
__global__ __launch_bounds__(256) void k_embed(const float* __restrict__ xP, const float* __restrict__ xF,
                                               const bf16* __restrict__ WT, const float* __restrict__ bias,
                                               bf16* __restrict__ oP, bf16* __restrict__ oF) {
    const int lane = threadIdx.x & 63, wv = threadIdx.x >> 6;
    const float* x = blockIdx.z ? xF : xP;
    bf16* o = blockIdx.z ? oF : oP;
    const int m0w = blockIdx.x * 128 + wv * 32;
    const int c0 = blockIdx.y * 64;
    const int koff = (lane >> 4) * 8;
    f32x4 acc[2][4];
#pragma unroll
    for (int m = 0; m < 2; ++m)
#pragma unroll
        for (int s = 0; s < 4; ++s) acc[m][s] = f32x4{0.f, 0.f, 0.f, 0.f};

    const float* xp0 = x + (size_t)(m0w + (lane & 15)) * Dd + koff;
#pragma unroll
    for (int kc = 0; kc < 4; ++kc) {
        bf16x8 a0, a1;
        {
            float4 f0 = *(const float4*)(xp0 + kc * 32);
            float4 f1 = *(const float4*)(xp0 + kc * 32 + 4);
            a0[0] = (bf16)f0.x; a0[1] = (bf16)f0.y; a0[2] = (bf16)f0.z; a0[3] = (bf16)f0.w;
            a0[4] = (bf16)f1.x; a0[5] = (bf16)f1.y; a0[6] = (bf16)f1.z; a0[7] = (bf16)f1.w;
            float4 g0 = *(const float4*)(xp0 + 16 * Dd + kc * 32);
            float4 g1 = *(const float4*)(xp0 + 16 * Dd + kc * 32 + 4);
            a1[0] = (bf16)g0.x; a1[1] = (bf16)g0.y; a1[2] = (bf16)g0.z; a1[3] = (bf16)g0.w;
            a1[4] = (bf16)g1.x; a1[5] = (bf16)g1.y; a1[6] = (bf16)g1.z; a1[7] = (bf16)g1.w;
        }
#pragma unroll
        for (int s = 0; s < 4; ++s) {
            bf16x8 b = *(const bf16x8*)(WT + (size_t)(c0 + s * 16 + (lane & 15)) * Dd + kc * 32 + koff);
            acc[0][s] = __builtin_amdgcn_mfma_f32_16x16x32_bf16(a0, b, acc[0][s], 0, 0, 0);
            acc[1][s] = __builtin_amdgcn_mfma_f32_16x16x32_bf16(a1, b, acc[1][s], 0, 0, 0);
        }
    }
#pragma unroll
    for (int m = 0; m < 2; ++m)
#pragma unroll
        for (int s = 0; s < 4; ++s) {
            int col = c0 + s * 16 + (lane & 15);
            float bv = bias[col];
#pragma unroll
            for (int r = 0; r < 4; ++r) {
                int row = m0w + m * 16 + (lane >> 4) * 4 + r;
                o[(size_t)row * Ee + col] = (bf16)fmaxf(acc[m][s][r] + bv, 0.0f);
            }
        }
}

// ---------------- persistent cooperative GRU (round-11 configuration, best measured) ----------------
// 256 blocks = 16 groups (im) x 16 col-blocks (in); XCD-affine remap. 4 waves/block: wv = rh
// (16-row slice). Each wave computes BOTH 16-col halves (f=0,1) of the block's 32 cols.
// Sync domain = (im, rh): 16 block-peers, one wave each, per-wave sc1 flags (64B stride),
// per-peer pipelined HSTEP waits. No per-step __syncthreads.
__global__ __launch_bounds__(256, 1) void k_gru_all(
    const bf16* __restrict__ embP, const bf16* __restrict__ embF, const float* __restrict__ noise,
    const bf16* __restrict__ WihE, const bf16* __restrict__ WhhE,
    const float* __restrict__ bIhE, const float* __restrict__ bHhE,
    const bf16* __restrict__ WihD, const bf16* __restrict__ WhhD,
    const float* __restrict__ bIhD, const float* __restrict__ bHhD,
    bf16* __restrict__ hA, bf16* __restrict__ hB, bf16* __restrict__ ys, unsigned* __restrict__ flags) {
    __shared__ bf16 Wih[6 * 8 * 64 * 8];    // 49152 B: [s=gate*2+f][kc8][lane]x8
    __shared__ bf16 Whh[6 * 16 * 64 * 8];   // 98304 B: [s=gate*2+f][kc16][lane]x8
    const int tid = threadIdx.x;
    const int lane = tid & 63, rh = tid >> 6;    // rh 0..3
    const int bid = blockIdx.x;
    const int im = (bid & 7) * 2 + (bid >> 7);   // group 0..15; xcd = bid&7
    const int in = (bid >> 3) & 15;              // col block 0..15
    const int rowb = im * 64 + rh * 16;
    const int arow0 = rowb + (lane & 15);
    const int koff = (lane >> 4) * 8;
    const int colc0 = in * 32 + (lane & 15);     // f=0 column; f=1 adds 16
    unsigned* dom = flags + ((size_t)im * 4 + rh) * 16 * 16;  // 16 flags x 64B

    const bf16x8* WihV = (const bf16x8*)Wih;
    const bf16x8* WhhV = (const bf16x8*)Whh;

    auto stage = [&](const bf16* WT, int Kdim, int KC, bf16* lds) {
        int total = 6 * KC * 64;
        for (int idx = tid; idx < total; idx += 256) {
            int ln = idx & 63;
            int kc = (idx >> 6) % KC;
            int s = (idx >> 6) / KC;
            int gate = s >> 1, f = s & 1;
            int col = gate * Hh + in * 32 + f * 16 + (ln & 15);
            int k = kc * 32 + (ln >> 4) * 8;
            *(bf16x8*)(lds + (size_t)idx * 8) = *(const bf16x8*)(WT + (size_t)col * Kdim + k);
        }
    };

    float bi[3][2], bh[3][2];
    auto load_bias = [&](const float* bIh, const float* bHh) {
#pragma unroll
        for (int g = 0; g < 3; ++g)
#pragma unroll
            for (int f = 0; f < 2; ++f) {
                int c = g * Hh + colc0 + f * 16;
                bi[g][f] = bIh[c];
                bh[g][f] = bHh[c];
            }
    };

    // per-WAVE release: my sc1 stores acked at L3 -> lane0 publishes seq. No block barrier.
    auto signal = [&](unsigned seq) {
        asm volatile("s_waitcnt vmcnt(0)" ::: "memory");
        if (lane == 0) {
            unsigned* fp = dom + in * 16;
            asm volatile("global_store_dword %0, %1, off sc1" :: "v"(fp), "v"(seq) : "memory");
        }
    };
    // one poll: lane k loads peer (k&15)'s flag -> 64-bit ballot (bit p valid via lane p)
    auto poll = [&](unsigned seq) -> unsigned long long {
        unsigned v;
        const unsigned* fp = dom + (lane & 15) * 16;
        asm volatile("global_load_dword %0, %1, off sc1\n\ts_waitcnt vmcnt(0)"
                     : "=&v"(v) : "v"(fp) : "memory");
        return __ballot((int)(v >= seq));
    };
    auto wait_all = [&](unsigned seq) {
        while (poll(seq) != ~0ULL) __builtin_amdgcn_s_sleep(2);
    };

    f32x4 aR[2], aZ[2], aNX[2], aNH[2];
    auto zacc = [&]() {
#pragma unroll
        for (int f = 0; f < 2; ++f) {
            aR[f] = f32x4{0.f, 0.f, 0.f, 0.f};
            aZ[f] = f32x4{0.f, 0.f, 0.f, 0.f};
            aNX[f] = f32x4{0.f, 0.f, 0.f, 0.f};
            aNH[f] = f32x4{0.f, 0.f, 0.f, 0.f};
        }
    };

    auto xp_phase = [&](const bf16* xp) {
        const bf16* ap = xp + (size_t)arow0 * Ee + koff;
#pragma unroll
        for (int kc = 0; kc < 8; ++kc) {
            bf16x8 a = *(const bf16x8*)(ap + kc * 32);
#pragma unroll
            for (int f = 0; f < 2; ++f) {
                aR[f] = __builtin_amdgcn_mfma_f32_16x16x32_bf16(a, WihV[((0 + f) * 8 + kc) * 64 + lane], aR[f], 0, 0, 0);
                aZ[f] = __builtin_amdgcn_mfma_f32_16x16x32_bf16(a, WihV[((2 + f) * 8 + kc) * 64 + lane], aZ[f], 0, 0, 0);
                aNX[f] = __builtin_amdgcn_mfma_f32_16x16x32_bf16(a, WihV[((4 + f) * 8 + kc) * 64 + lane], aNX[f], 0, 0, 0);
            }
        }
    };

    // hW with per-peer pipelined waits: K-chunk kc=p holds peer block p's columns (flag p).
    auto hw_phase = [&](const bf16* hp, unsigned seq) {
        const bf16* h0p = hp + (size_t)arow0 * Hh + koff;
        bf16x8 h0[16];
        unsigned long long rdy = poll(seq);
#define HSTEP(p, OFF) \
        while (!((rdy >> p) & 1ULL)) { __builtin_amdgcn_s_sleep(2); rdy = poll(seq); } \
        LD_SC(h0[p], h0p, OFF);
        HSTEP(0, 0)    HSTEP(1, 64)   HSTEP(2, 128)  HSTEP(3, 192)
        HSTEP(4, 256)  HSTEP(5, 320)  HSTEP(6, 384)  HSTEP(7, 448)
        HSTEP(8, 512)  HSTEP(9, 576)  HSTEP(10, 640) HSTEP(11, 704)
        HSTEP(12, 768) HSTEP(13, 832) HSTEP(14, 896) HSTEP(15, 960)
#undef HSTEP
        asm volatile("s_waitcnt vmcnt(0)" ::: "memory");
        __builtin_amdgcn_sched_barrier(0);
#pragma unroll
        for (int kc = 0; kc < 16; ++kc) {
#pragma unroll
            for (int f = 0; f < 2; ++f) {
                aR[f] = __builtin_amdgcn_mfma_f32_16x16x32_bf16(h0[kc], WhhV[((0 + f) * 16 + kc) * 64 + lane], aR[f], 0, 0, 0);
                aZ[f] = __builtin_amdgcn_mfma_f32_16x16x32_bf16(h0[kc], WhhV[((2 + f) * 16 + kc) * 64 + lane], aZ[f], 0, 0, 0);
                aNH[f] = __builtin_amdgcn_mfma_f32_16x16x32_bf16(h0[kc], WhhV[((4 + f) * 16 + kc) * 64 + lane], aNH[f], 0, 0, 0);
            }
        }
    };

    float hreg[8];
#pragma unroll
    for (int i = 0; i < 8; ++i) hreg[i] = 0.0f;

    auto epi = [&](bf16* op) {
#pragma unroll
        for (int f = 0; f < 2; ++f) {
            bf16* stb = op + (size_t)(rowb + (lane >> 4) * 4) * Hh + colc0 + f * 16;
            unsigned short us[4];
#pragma unroll
            for (int r = 0; r < 4; ++r) {
                float rg = sigmf(aR[f][r] + bi[0][f] + bh[0][f]);
                float zg = sigmf(aZ[f][r] + bi[1][f] + bh[1][f]);
                float ng = tanhfast(aNX[f][r] + bi[2][f] + rg * (aNH[f][r] + bh[2][f]));
                float hv = (1.0f - zg) * ng + zg * hreg[f * 4 + r];
                hreg[f * 4 + r] = hv;
                us[r] = __builtin_bit_cast(unsigned short, (bf16)hv);
            }
            ST_SC(stb, 0, us[0]);
            ST_SC(stb, 1024, us[1]);
            ST_SC(stb, 2048, us[2]);
            ST_SC(stb, 3072, us[3]);
        }
    };

    // ---------- encoder ----------
    stage(WihE, Ee, 8, Wih);
    stage(WhhE, Hh, 16, Whh);
    load_bias(bIhE, bHhE);
    __syncthreads();

#pragma unroll 1
    for (int t = 0; t < Tt; ++t) {
        zacc();
        xp_phase(embP + (size_t)t * Bb * Ee);
        if (t > 0) hw_phase(((t - 1) & 1) ? hB : hA, (unsigned)t);
        epi((t & 1) ? hB : hA);
        signal((unsigned)(t + 1));  // seq 1..64
    }

    // ---------- hidden = h_enc + noise; switch to decoder weights ----------
    wait_all((unsigned)Tt);  // (im,rh) peers done with enc step 63 (incl. hA reads)
    {
#pragma unroll
        for (int f = 0; f < 2; ++f) {
            bf16* stb = hA + (size_t)(rowb + (lane >> 4) * 4) * Hh + colc0 + f * 16;
            unsigned short us[4];
#pragma unroll
            for (int r = 0; r < 4; ++r) {
                int row = rowb + (lane >> 4) * 4 + r;
                float v = hreg[f * 4 + r] + noise[(size_t)row * Hh + colc0 + f * 16];
                hreg[f * 4 + r] = v;
                us[r] = __builtin_bit_cast(unsigned short, (bf16)v);
            }
            ST_SC(stb, 0, us[0]);
            ST_SC(stb, 1024, us[1]);
            ST_SC(stb, 2048, us[2]);
            ST_SC(stb, 3072, us[3]);
        }
    }
    __syncthreads();  // all waves of this block past their enc LDS reads
    stage(WihD, Ee, 8, Wih);
    stage(WhhD, Hh, 16, Whh);
    __syncthreads();  // decoder LDS staged before any wave's dec reads
    load_bias(bIhD, bHhD);
    signal((unsigned)(Tt + 1));  // seq 65: hA(+noise) visible

    // ---------- decoder; ys[t] doubles as the bf16 hidden chain ----------
#pragma unroll 1
    for (int t = 0; t < Tt; ++t) {
        zacc();
        if (t > 0) xp_phase(embF + (size_t)(t - 1) * Bb * Ee);
        hw_phase(t ? ys + (size_t)(t - 1) * Bb * Hh : hA, (unsigned)(Tt + 1 + t));  // seq 65+t
        epi(ys + (size_t)t * Bb * Hh);
        if (t < Tt - 1) signal((unsigned)(Tt + 2 + t));  // seq 66..128
    }
}

// ---------------- out = ys @ W_out + b_out; 64 rows/wave ----------------
__global__ __launch_bounds__(256) void k_out(const bf16* __restrict__ ys, const bf16* __restrict__ WT,
                                             const float* __restrict__ bias, float* __restrict__ out) {
    const int lane = threadIdx.x & 63, wv = threadIdx.x >> 6;
    const int m0w = blockIdx.x * 256 + wv * 64;
    const int c0 = blockIdx.y * 64;
    const int koff = (lane >> 4) * 8;
    f32x4 acc[4][4];
#pragma unroll
    for (int m = 0; m < 4; ++m)
#pragma unroll
        for (int s = 0; s < 4; ++s) acc[m][s] = f32x4{0.f, 0.f, 0.f, 0.f};

    const bf16* ap = ys + (size_t)(m0w + (lane & 15)) * Hh + koff;
#pragma unroll
    for (int kc = 0; kc < 16; ++kc) {
        bf16x8 a0 = *(const bf16x8*)(ap + kc * 32);
        bf16x8 a1 = *(const bf16x8*)(ap + 16 * Hh + kc * 32);
        bf16x8 a2 = *(const bf16x8*)(ap + 32 * Hh + kc * 32);
        bf16x8 a3 = *(const bf16x8*)(ap + 48 * Hh + kc * 32);
#pragma unroll
        for (int s = 0; s < 4; ++s) {
            bf16x8 b = *(const bf16x8*)(WT + (size_t)(c0 + s * 16 + (lane & 15)) * Hh + kc * 32 + koff);
            acc[0][s] = __builtin_amdgcn_mfma_f32_16x16x32_bf16(a0, b, acc[0][s], 0, 0, 0);
            acc[1][s] = __builtin_amdgcn_mfma_f32_16x16x32_bf16(a1, b, acc[1][s], 0, 0, 0);
            acc[2][s] = __builtin_amdgcn_mfma_f32_16x16x32_bf16(a2, b, acc[2][s], 0, 0, 0);
            acc[3][s] = __builtin_amdgcn_mfma_f32_16x16x32_bf16(a3, b, acc[3][s], 0, 0, 0);
        }
    }
#pragma unroll
    for (int m = 0; m < 4; ++m)
#pragma unroll
        for (int s = 0; s < 4; ++s) {
            int col = c0 + s * 16 + (lane & 15);
            float bv = bias[col];
#pragma unroll
            for (int r = 0; r < 4; ++r) {
                int row = m0w + m * 16 + (lane >> 4) * 4 + r;
                out[(size_t)row * Dd + col] = acc[m][s][r] + bv;
            }
        }
}

extern "C" void kernel_launch(void* const* d_in, const int* in_sizes, int n_in,
                              void* d_out, int out_size, void* d_ws, size_t ws_size,
                              hipStream_t stream) {
    const float* past = (const float*)d_in[0];
    const float* fut = (const float*)d_in[1];
    const float* noise = (const float*)d_in[2];
    const float* W_emb = (const float*)d_in[3];
    const float* b_emb = (const float*)d_in[4];
    const float* W_ih_enc = (const float*)d_in[5];
    const float* W_hh_enc = (const float*)d_in[6];
    const float* b_ih_enc = (const float*)d_in[7];
    const float* b_hh_enc = (const float*)d_in[8];
    const float* W_ih_dec = (const float*)d_in[9];
    const float* W_hh_dec = (const float*)d_in[10];
    const float* b_ih_dec = (const float*)d_in[11];
    const float* b_hh_dec = (const float*)d_in[12];
    const float* W_out = (const float*)d_in[13];
    const float* b_out = (const float*)d_in[14];
    float* out = (float*)d_out;

    char* w = (char*)d_ws;
    auto alloc = [&](size_t bytes) {
        char* p = w;
        w += (bytes + 255) & ~(size_t)255;
        return p;
    };
    bf16* embP = (bf16*)alloc((size_t)Tt * Bb * Ee * 2);
    bf16* embF = (bf16*)alloc((size_t)Tt * Bb * Ee * 2);
    bf16* ys = (bf16*)alloc((size_t)Tt * Bb * Hh * 2);
    bf16* hA = (bf16*)alloc((size_t)Bb * Hh * 2);
    bf16* hB = (bf16*)alloc((size_t)Bb * Hh * 2);
    bf16* WembT = (bf16*)alloc((size_t)Ee * Dd * 2);
    bf16* WihEncT = (bf16*)alloc((size_t)H3 * Ee * 2);
    bf16* WhhEncT = (bf16*)alloc((size_t)H3 * Hh * 2);
    bf16* WihDecT = (bf16*)alloc((size_t)H3 * Ee * 2);
    bf16* WhhDecT = (bf16*)alloc((size_t)H3 * Hh * 2);
    bf16* WoutT = (bf16*)alloc((size_t)Dd * Hh * 2);
    unsigned* flags = (unsigned*)alloc(16 * 4 * 16 * 16 * sizeof(unsigned));  // [im][rh][in], 64B stride

    // weight prep (all six transposes fused)
    k_prep<<<9600, 256, 0, stream>>>(W_emb, W_ih_enc, W_hh_enc, W_ih_dec, W_hh_dec, W_out,
                                     WembT, WihEncT, WhhEncT, WihDecT, WhhDecT, WoutT);

    // embeddings (past + future fused)
    k_embed<<<dim3(Tt * Bb / 128, Ee / 64, 2), 256, 0, stream>>>(past, fut, WembT, b_emb, embP, embF);

    // reset sequence flags
    hipMemsetAsync(flags, 0, 16 * 4 * 16 * 16 * sizeof(unsigned), stream);

    // cooperative persistent recurrent kernel: 256 blocks x 256 threads
    void* args[] = {(void*)&embP, (void*)&embF, (void*)&noise,
                    (void*)&WihEncT, (void*)&WhhEncT, (void*)&b_ih_enc, (void*)&b_hh_enc,
                    (void*)&WihDecT, (void*)&WhhDecT, (void*)&b_ih_dec, (void*)&b_hh_dec,
                    (void*)&hA, (void*)&hB, (void*)&ys, (void*)&flags};
    hipLaunchCooperativeKernel((const void*)k_gru_all, dim3(256), dim3(256), args, 0, stream);

    // output projection
    k_out<<<dim3(Tt * Bb / 256, Dd / 64), 256, 0, stream>>>(ys, WoutT, b_out, out);
}